// Round 1
// baseline (553.225 us; speedup 1.0000x reference)
//
#include <hip/hip_runtime.h>
#include <math.h>

#define B_ 32
#define HW_ 4096
#define N_ 16
#define C_ 128
#define F_ 512
#define ITERS_ 3
#define EPS_LN 1e-5f
#define EPS_ATTN 1e-5f

typedef __attribute__((ext_vector_type(8))) short short8;
typedef __attribute__((ext_vector_type(4))) float f32x4;

static __device__ __forceinline__ unsigned short f2b(float f) {
    union { float f; unsigned u; } v; v.f = f;
    unsigned r = v.u + 0x7fffu + ((v.u >> 16) & 1u);
    return (unsigned short)(r >> 16);
}

// ---------------------------------------------------------------------------
// Kernel 1: kv = LN(inp); K = kv@Wk^T -> bf16 [b][hw][c];
//           V = kv@Wv^T -> bf16 transposed [b][c][hw]
// 64 rows per block, 256 threads (4 waves), MFMA 16x16x32 bf16.
// ---------------------------------------------------------------------------
__global__ __launch_bounds__(256) void k_kvproj(
    const float* __restrict__ inp, const float* __restrict__ lng,
    const float* __restrict__ lnb, const float* __restrict__ Wk,
    const float* __restrict__ Wv, unsigned short* __restrict__ Kbf,
    unsigned short* __restrict__ Vt)
{
    __shared__ __align__(16) unsigned short A_lds[64 * 136];   // padded stride
    __shared__ __align__(16) unsigned short W_lds[128 * 136];  // padded stride
    const int tid = threadIdx.x;
    const int wave = tid >> 6, lane = tid & 63;
    const int l15 = lane & 15, q4 = lane >> 4;
    const int kof = q4 * 8;
    const int tile0 = blockIdx.x * 64;       // global row base (b*HW + hw)
    const int b = tile0 >> 12;
    const int hwbase = tile0 & (HW_ - 1);

    // ---- LN stage: 4 threads per row, 32 elems each ----
    {
        int r = tid >> 2, part = tid & 3;
        int row = tile0 + r;
        const float4* x4 = (const float4*)(inp + row * C_ + part * 32);
        float4 xv[8];
        float s = 0.f, ss = 0.f;
#pragma unroll
        for (int i = 0; i < 8; i++) {
            xv[i] = x4[i];
            s += xv[i].x + xv[i].y + xv[i].z + xv[i].w;
            ss += xv[i].x * xv[i].x + xv[i].y * xv[i].y + xv[i].z * xv[i].z + xv[i].w * xv[i].w;
        }
        s += __shfl_xor(s, 1);  s += __shfl_xor(s, 2);
        ss += __shfl_xor(ss, 1); ss += __shfl_xor(ss, 2);
        float mean = s * (1.f / 128.f);
        float var = ss * (1.f / 128.f) - mean * mean;
        float rstd = rsqrtf(var + EPS_LN);
        const float4* g4 = (const float4*)(lng + part * 32);
        const float4* b4 = (const float4*)(lnb + part * 32);
        unsigned* Au = (unsigned*)A_lds;
        int ubase = r * 68 + part * 16;
#pragma unroll
        for (int i = 0; i < 8; i++) {
            float4 gg = g4[i], bb = b4[i];
            float n0 = (xv[i].x - mean) * rstd * gg.x + bb.x;
            float n1 = (xv[i].y - mean) * rstd * gg.y + bb.y;
            float n2 = (xv[i].z - mean) * rstd * gg.z + bb.z;
            float n3 = (xv[i].w - mean) * rstd * gg.w + bb.w;
            Au[ubase + i * 2]     = (unsigned)f2b(n0) | ((unsigned)f2b(n1) << 16);
            Au[ubase + i * 2 + 1] = (unsigned)f2b(n2) | ((unsigned)f2b(n3) << 16);
        }
    }
    // ---- stage Wk ----
    {
        int c = tid >> 1, half = tid & 1;
        const float4* src = (const float4*)(Wk + c * 128 + half * 64);
        unsigned* Wu = (unsigned*)W_lds + c * 68 + half * 32;
#pragma unroll
        for (int i = 0; i < 16; i++) {
            float4 w = src[i];
            Wu[i * 2]     = (unsigned)f2b(w.x) | ((unsigned)f2b(w.y) << 16);
            Wu[i * 2 + 1] = (unsigned)f2b(w.z) | ((unsigned)f2b(w.w) << 16);
        }
    }
    __syncthreads();

    // A fragments (reused for both K and V phases)
    const int m_row = (wave << 4) + l15;
    short8 af[4];
#pragma unroll
    for (int ks = 0; ks < 4; ks++)
        af[ks] = *(const short8*)&A_lds[m_row * 136 + ks * 32 + kof];

    f32x4 acc[8];
    // ---- K phase ----
#pragma unroll
    for (int nt = 0; nt < 8; nt++) {
        acc[nt] = (f32x4){0.f, 0.f, 0.f, 0.f};
#pragma unroll
        for (int ks = 0; ks < 4; ks++) {
            short8 bf = *(const short8*)&W_lds[(nt * 16 + l15) * 136 + ks * 32 + kof];
            acc[nt] = __builtin_amdgcn_mfma_f32_16x16x32_bf16(af[ks], bf, acc[nt], 0, 0, 0);
        }
    }
    {
        int hwr0 = hwbase + (wave << 4);
#pragma unroll
        for (int nt = 0; nt < 8; nt++) {
            int c = nt * 16 + l15;
#pragma unroll
            for (int i = 0; i < 4; i++) {
                int m = (q4 << 2) + i;
                Kbf[(b * HW_ + hwr0 + m) * C_ + c] = f2b(acc[nt][i]);
            }
        }
    }
    __syncthreads();
    // ---- stage Wv ----
    {
        int c = tid >> 1, half = tid & 1;
        const float4* src = (const float4*)(Wv + c * 128 + half * 64);
        unsigned* Wu = (unsigned*)W_lds + c * 68 + half * 32;
#pragma unroll
        for (int i = 0; i < 16; i++) {
            float4 w = src[i];
            Wu[i * 2]     = (unsigned)f2b(w.x) | ((unsigned)f2b(w.y) << 16);
            Wu[i * 2 + 1] = (unsigned)f2b(w.z) | ((unsigned)f2b(w.w) << 16);
        }
    }
    __syncthreads();
    // ---- V phase ----
#pragma unroll
    for (int nt = 0; nt < 8; nt++) {
        acc[nt] = (f32x4){0.f, 0.f, 0.f, 0.f};
#pragma unroll
        for (int ks = 0; ks < 4; ks++) {
            short8 bf = *(const short8*)&W_lds[(nt * 16 + l15) * 136 + ks * 32 + kof];
            acc[nt] = __builtin_amdgcn_mfma_f32_16x16x32_bf16(af[ks], bf, acc[nt], 0, 0, 0);
        }
    }
    __syncthreads();   // everyone done reading W_lds; reuse it as transpose buffer
    {
        unsigned short* Vl = W_lds;  // [64 hw][128 c], stride 128
#pragma unroll
        for (int nt = 0; nt < 8; nt++) {
            int c = nt * 16 + l15;
#pragma unroll
            for (int i = 0; i < 4; i++) {
                int m = (wave << 4) + (q4 << 2) + i;
                Vl[m * 128 + c] = f2b(acc[nt][i]);
            }
        }
    }
    __syncthreads();
    {
        const unsigned short* Vl = W_lds;
        int c = tid >> 1, h0 = (tid & 1) * 32;
        int base = (b * C_ + c) * HW_ + hwbase + h0;
#pragma unroll
        for (int i = 0; i < 16; i++) {
            unsigned lo = Vl[(h0 + 2 * i) * 128 + c];
            unsigned hi = Vl[(h0 + 2 * i + 1) * 128 + c];
            *(unsigned*)&Vt[base + 2 * i] = lo | (hi << 16);
        }
    }
}

// ---------------------------------------------------------------------------
// Kernel 2 (per iter): qn = (LN(q)*g+b) @ Wq^T * scale -> bf16 [b][n][c];
// also zero U/rowsum; on first iter copy query -> q_buf.
// One block per batch, 256 threads.
// ---------------------------------------------------------------------------
__global__ __launch_bounds__(256) void k_qprep(
    const float* __restrict__ query, float* __restrict__ q_buf,
    const float* __restrict__ lng, const float* __restrict__ lnb,
    const float* __restrict__ Wq, unsigned short* __restrict__ qn,
    float* __restrict__ U, float* __restrict__ rowsum, int first)
{
    __shared__ __align__(16) float xq[16 * 128];
    int b = blockIdx.x, tid = threadIdx.x;

    if (first) {
        const float4* src = (const float4*)(query + b * 2048);
        float4* dst = (float4*)(q_buf + b * 2048);
#pragma unroll
        for (int i = 0; i < 2; i++) dst[tid + i * 256] = src[tid + i * 256];
    }
    {
        float4* Uz = (float4*)(U + b * 2048);
        f32x4 z4 = {0.f, 0.f, 0.f, 0.f};
#pragma unroll
        for (int i = 0; i < 2; i++) Uz[tid + i * 256] = *(float4*)&z4;
        if (tid < 16) rowsum[b * 16 + tid] = 0.f;
    }

    int n = tid >> 4, part = tid & 15;
    int row = b * 16 + n;
    const float* src = first ? query : q_buf;
    const float4* x4 = (const float4*)(src + row * 128 + part * 8);
    float4 x0 = x4[0], x1 = x4[1];
    float s = x0.x + x0.y + x0.z + x0.w + x1.x + x1.y + x1.z + x1.w;
    float ss = x0.x * x0.x + x0.y * x0.y + x0.z * x0.z + x0.w * x0.w +
               x1.x * x1.x + x1.y * x1.y + x1.z * x1.z + x1.w * x1.w;
    s += __shfl_xor(s, 1); s += __shfl_xor(s, 2); s += __shfl_xor(s, 4); s += __shfl_xor(s, 8);
    ss += __shfl_xor(ss, 1); ss += __shfl_xor(ss, 2); ss += __shfl_xor(ss, 4); ss += __shfl_xor(ss, 8);
    float mean = s * (1.f / 128.f);
    float var = ss * (1.f / 128.f) - mean * mean;
    float rstd = rsqrtf(var + EPS_LN);
    const float4* g4 = (const float4*)(lng + part * 8);
    const float4* b4 = (const float4*)(lnb + part * 8);
    float4* xrow = (float4*)&xq[n * 128];
    float4 g0 = g4[0], g1 = g4[1], bb0 = b4[0], bb1 = b4[1];
    float4 o0, o1;
    o0.x = (x0.x - mean) * rstd * g0.x + bb0.x;
    o0.y = (x0.y - mean) * rstd * g0.y + bb0.y;
    o0.z = (x0.z - mean) * rstd * g0.z + bb0.z;
    o0.w = (x0.w - mean) * rstd * g0.w + bb0.w;
    o1.x = (x1.x - mean) * rstd * g1.x + bb1.x;
    o1.y = (x1.y - mean) * rstd * g1.y + bb1.y;
    o1.z = (x1.z - mean) * rstd * g1.z + bb1.z;
    o1.w = (x1.w - mean) * rstd * g1.w + bb1.w;
    xrow[part * 2] = o0;
    xrow[part * 2 + 1] = o1;
    __syncthreads();

    float o[8] = {0.f, 0.f, 0.f, 0.f, 0.f, 0.f, 0.f, 0.f};
    const float4* xv4 = (const float4*)&xq[n * 128];
#pragma unroll 4
    for (int j = 0; j < 32; j++) {
        float4 xv = xv4[j];
#pragma unroll
        for (int i = 0; i < 8; i++) {
            float4 w = ((const float4*)(Wq + (part * 8 + i) * 128))[j];
            o[i] += w.x * xv.x + w.y * xv.y + w.z * xv.z + w.w * xv.w;
        }
    }
    const float scale = 0.08838834764831845f;  // 128^-0.5
#pragma unroll
    for (int i = 0; i < 8; i++)
        qn[row * 128 + part * 8 + i] = f2b(o[i] * scale);
}

// ---------------------------------------------------------------------------
// Kernel 3 (per iter): fused logits -> column softmax (over 16 slots) ->
// a0 (+ optional output) -> rowsum + U accumulation. 128 hw per block,
// 32 hw per wave. grid (HW/128, B).
// ---------------------------------------------------------------------------
__global__ __launch_bounds__(256) void k_attn(
    const unsigned short* __restrict__ qn, const unsigned short* __restrict__ Kbf,
    const unsigned short* __restrict__ Vt, float* __restrict__ U,
    float* __restrict__ rowsum, float* __restrict__ a0_out, int last)
{
    __shared__ __align__(16) unsigned short P[4][16][32];   // per-wave a0 tile (bf16)
    __shared__ __align__(16) float Ul[4][2048];              // per-wave u^T partials
    int b = blockIdx.y, tid = threadIdx.x;
    int wave = tid >> 6, lane = tid & 63;
    int l15 = lane & 15, q4 = lane >> 4;
    int kof = q4 * 8;
    int hw0 = blockIdx.x * 128 + wave * 32;

    short8 aq[4];
#pragma unroll
    for (int ks = 0; ks < 4; ks++)
        aq[ks] = *(const short8*)&qn[(b * 16 + l15) * 128 + ks * 32 + kof];

    float rs[4] = {0.f, 0.f, 0.f, 0.f};
#pragma unroll
    for (int s = 0; s < 2; s++) {
        int hwt = hw0 + s * 16;
        f32x4 sa = {0.f, 0.f, 0.f, 0.f};
#pragma unroll
        for (int ks = 0; ks < 4; ks++) {
            short8 bk = *(const short8*)&Kbf[(b * HW_ + hwt + l15) * C_ + ks * 32 + kof];
            sa = __builtin_amdgcn_mfma_f32_16x16x32_bf16(aq[ks], bk, sa, 0, 0, 0);
        }
        // softmax over the 16 slots of this lane's column (l15 -> hw)
        float mx = fmaxf(fmaxf(sa[0], sa[1]), fmaxf(sa[2], sa[3]));
        mx = fmaxf(mx, __shfl_xor(mx, 16));
        mx = fmaxf(mx, __shfl_xor(mx, 32));
        float e[4]; float ssum = 0.f;
#pragma unroll
        for (int i = 0; i < 4; i++) { e[i] = __expf(sa[i] - mx); ssum += e[i]; }
        ssum += __shfl_xor(ssum, 16);
        ssum += __shfl_xor(ssum, 32);
        float inv = 1.f / ssum;
#pragma unroll
        for (int i = 0; i < 4; i++) {
            float a0v = e[i] * inv;
            rs[i] += a0v;
            if (last) a0_out[(b * 16 + q4 * 4 + i) * HW_ + hwt + l15] = a0v;
            P[wave][q4 * 4 + i][s * 16 + l15] = f2b(a0v);
        }
    }
    __syncthreads();
    // u^T accumulation: D2[c][q] += sum_hw Vt[c][hw] * a0[q][hw]
    short8 bp = *(const short8*)&P[wave][l15][kof];
    f32x4 uacc[8];
#pragma unroll
    for (int ct = 0; ct < 8; ct++) {
        uacc[ct] = (f32x4){0.f, 0.f, 0.f, 0.f};
        short8 av = *(const short8*)&Vt[(b * C_ + ct * 16 + l15) * HW_ + hw0 + kof];
        uacc[ct] = __builtin_amdgcn_mfma_f32_16x16x32_bf16(av, bp, uacc[ct], 0, 0, 0);
    }
    // stash per-wave partials, reduce across waves, one atomic per cell
#pragma unroll
    for (int ct = 0; ct < 8; ct++) {
        int c = ct * 16 + q4 * 4;
#pragma unroll
        for (int i = 0; i < 4; i++)
            Ul[wave][(c + i) * 16 + l15] = uacc[ct][i];
    }
    __syncthreads();
#pragma unroll
    for (int i = 0; i < 8; i++) {
        int idx = tid + i * 256;              // idx = c*16 + q
        float v = Ul[0][idx] + Ul[1][idx] + Ul[2][idx] + Ul[3][idx];
        int c = idx >> 4, q = idx & 15;
        atomicAdd(&U[b * 2048 + q * 128 + c], v);
    }
    // rowsum reduce over the 16 columns of this wave
#pragma unroll
    for (int i = 0; i < 4; i++) {
        rs[i] += __shfl_xor(rs[i], 1);
        rs[i] += __shfl_xor(rs[i], 2);
        rs[i] += __shfl_xor(rs[i], 4);
        rs[i] += __shfl_xor(rs[i], 8);
    }
    if (l15 == 0) {
#pragma unroll
        for (int i = 0; i < 4; i++)
            atomicAdd(&rowsum[b * 16 + q4 * 4 + i], rs[i]);
    }
}

// ---------------------------------------------------------------------------
// Kernel 4 (per iter): u = U/(rowsum+eps); y = GRU(u, q); z = LN2(y);
// q_new = y + FFN(z). 2 rows per block, 256 threads. fp32.
// ---------------------------------------------------------------------------
__global__ __launch_bounds__(256) void k_tail(
    const float* __restrict__ U, const float* __restrict__ rowsum,
    float* __restrict__ q_buf,
    const float* __restrict__ wih, const float* __restrict__ whh,
    const float* __restrict__ bih, const float* __restrict__ bhh,
    const float* __restrict__ ln2g, const float* __restrict__ ln2b,
    const float* __restrict__ w1, const float* __restrict__ b1,
    const float* __restrict__ w2, const float* __restrict__ b2,
    float* __restrict__ out_q, int last)
{
    __shared__ __align__(16) float u_l[2][128];
    __shared__ __align__(16) float h_l[2][128];
    __shared__ __align__(16) float g_l[2][768];
    __shared__ __align__(16) float z_l[2][128];
    __shared__ __align__(16) float y_l[2][128];
    __shared__ __align__(16) float h1_l[2][512];
    __shared__ float stats[2][2];
    int tid = threadIdx.x;
    int row0 = blockIdx.x * 2;
    {
        int r = tid >> 7, c = tid & 127;
        int row = row0 + r;
        float rsv = rowsum[row];
        u_l[r][c] = U[row * 128 + c] / (rsv + EPS_ATTN);
        h_l[r][c] = q_buf[row * 128 + c];
    }
    __syncthreads();
    // GRU input/hidden GEMMs: 768 output cols, weight row shared by both rows
#pragma unroll
    for (int o3 = 0; o3 < 3; o3++) {
        int o = tid + o3 * 256;
        const float* wrow;
        const float* srcbase;
        float bias;
        if (o < 384) { wrow = wih + o * 128; srcbase = &u_l[0][0]; bias = bih[o]; }
        else         { wrow = whh + (o - 384) * 128; srcbase = &h_l[0][0]; bias = bhh[o - 384]; }
        const float4* w4 = (const float4*)wrow;
        const float4* s0 = (const float4*)srcbase;
        const float4* s1 = (const float4*)(srcbase + 128);
        float a0acc = 0.f, a1acc = 0.f;
#pragma unroll 8
        for (int j = 0; j < 32; j++) {
            float4 w = w4[j], a = s0[j], bb = s1[j];
            a0acc += w.x * a.x + w.y * a.y + w.z * a.z + w.w * a.w;
            a1acc += w.x * bb.x + w.y * bb.y + w.z * bb.z + w.w * bb.w;
        }
        g_l[0][o] = a0acc + bias;
        g_l[1][o] = a1acc + bias;
    }
    __syncthreads();
    {
        int r = tid >> 7, c = tid & 127;
        float ir = g_l[r][c], iz = g_l[r][128 + c], in_ = g_l[r][256 + c];
        float hr = g_l[r][384 + c], hz = g_l[r][512 + c], hn = g_l[r][640 + c];
        float rr = 1.f / (1.f + expf(-(ir + hr)));
        float zz = 1.f / (1.f + expf(-(iz + hz)));
        float nn = tanhf(in_ + rr * hn);
        y_l[r][c] = (1.f - zz) * nn + zz * h_l[r][c];
    }
    __syncthreads();
    if (tid < 128) {
        int w = tid >> 6, lane = tid & 63;
        float v0 = y_l[w][lane], v1 = y_l[w][lane + 64];
        float s = v0 + v1, ss = v0 * v0 + v1 * v1;
#pragma unroll
        for (int off = 1; off < 64; off <<= 1) {
            s += __shfl_xor(s, off);
            ss += __shfl_xor(ss, off);
        }
        if (lane == 0) {
            float mean = s * (1.f / 128.f);
            float var = ss * (1.f / 128.f) - mean * mean;
            stats[w][0] = mean;
            stats[w][1] = rsqrtf(var + EPS_LN);
        }
    }
    __syncthreads();
    {
        int r = tid >> 7, c = tid & 127;
        z_l[r][c] = (y_l[r][c] - stats[r][0]) * stats[r][1] * ln2g[c] + ln2b[c];
    }
    __syncthreads();
    // FFN1
#pragma unroll
    for (int f2i = 0; f2i < 2; f2i++) {
        int f = tid + f2i * 256;
        const float4* w4 = (const float4*)(w1 + f * 128);
        const float4* s0 = (const float4*)&z_l[0][0];
        const float4* s1 = (const float4*)&z_l[1][0];
        float a0acc = 0.f, a1acc = 0.f;
#pragma unroll 8
        for (int j = 0; j < 32; j++) {
            float4 w = w4[j], a = s0[j], bb = s1[j];
            a0acc += w.x * a.x + w.y * a.y + w.z * a.z + w.w * a.w;
            a1acc += w.x * bb.x + w.y * bb.y + w.z * bb.z + w.w * bb.w;
        }
        float bv = b1[f];
        h1_l[0][f] = fmaxf(a0acc + bv, 0.f);
        h1_l[1][f] = fmaxf(a1acc + bv, 0.f);
    }
    __syncthreads();
    // FFN2 + residual
    {
        int r = tid >> 7, c = tid & 127;
        const float4* w4 = (const float4*)(w2 + c * 512);
        const float4* hh = (const float4*)&h1_l[r][0];
        float acc = 0.f;
#pragma unroll 8
        for (int j = 0; j < 128; j++) {
            float4 w = w4[j], v = hh[j];
            acc += w.x * v.x + w.y * v.y + w.z * v.z + w.w * v.w;
        }
        float q_new = y_l[r][c] + acc + b2[c];
        int row = row0 + r;
        q_buf[row * 128 + c] = q_new;
        if (last) out_q[row * 128 + c] = q_new;
    }
}

// ---------------------------------------------------------------------------
extern "C" void kernel_launch(void* const* d_in, const int* in_sizes, int n_in,
                              void* d_out, int out_size, void* d_ws, size_t ws_size,
                              hipStream_t stream) {
    const float* inp     = (const float*)d_in[0];
    const float* query   = (const float*)d_in[1];
    const float* ln_kv_g = (const float*)d_in[2];
    const float* ln_kv_b = (const float*)d_in[3];
    const float* Wk      = (const float*)d_in[4];
    const float* Wv      = (const float*)d_in[5];
    const float* ln_q_g  = (const float*)d_in[6];
    const float* ln_q_b  = (const float*)d_in[7];
    const float* Wq      = (const float*)d_in[8];
    const float* gru_wih = (const float*)d_in[9];
    const float* gru_whh = (const float*)d_in[10];
    const float* gru_bih = (const float*)d_in[11];
    const float* gru_bhh = (const float*)d_in[12];
    const float* ln2_g   = (const float*)d_in[13];
    const float* ln2_b   = (const float*)d_in[14];
    const float* ffn_w1  = (const float*)d_in[15];
    const float* ffn_b1  = (const float*)d_in[16];
    const float* ffn_w2  = (const float*)d_in[17];
    const float* ffn_b2  = (const float*)d_in[18];

    char* ws = (char*)d_ws;
    unsigned short* Kbf = (unsigned short*)ws;                    // 33554432 B
    unsigned short* Vt  = (unsigned short*)(ws + 33554432);       // 33554432 B
    unsigned short* qn  = (unsigned short*)(ws + 67108864);       // 131072 B
    float* q_buf  = (float*)(ws + 67239936);                      // 262144 B
    float* U      = (float*)(ws + 67502080);                      // 262144 B
    float* rowsum = (float*)(ws + 67764224);                      // 2048 B

    float* out_q  = (float*)d_out;
    float* out_a0 = out_q + B_ * N_ * C_;

    k_kvproj<<<dim3((B_ * HW_) / 64), dim3(256), 0, stream>>>(
        inp, ln_kv_g, ln_kv_b, Wk, Wv, Kbf, Vt);

    for (int it = 0; it < ITERS_; it++) {
        k_qprep<<<dim3(B_), dim3(256), 0, stream>>>(
            query, q_buf, ln_q_g, ln_q_b, Wq, qn, U, rowsum, it == 0 ? 1 : 0);
        k_attn<<<dim3(HW_ / 128, B_), dim3(256), 0, stream>>>(
            qn, Kbf, Vt, U, rowsum, out_a0, it == ITERS_ - 1 ? 1 : 0);
        k_tail<<<dim3((B_ * N_) / 2), dim3(256), 0, stream>>>(
            U, rowsum, q_buf, gru_wih, gru_whh, gru_bih, gru_bhh,
            ln2_g, ln2_b, ffn_w1, ffn_b1, ffn_w2, ffn_b2,
            out_q, it == ITERS_ - 1 ? 1 : 0);
    }
}